// Round 13
// baseline (52.257 us; speedup 1.0000x reference)
//
#include <hip/hip_runtime.h>
#include <hip/hip_bf16.h>

#define N 8192
#define D 256
#define SP 8
#define NCHK 16                // 16 chunks of 64 cols = 1024 cols per panel
#define LOG2E 1.44269504088896f

typedef int   i32x8 __attribute__((ext_vector_type(8)));
typedef float f32x4 __attribute__((ext_vector_type(4)));

// ---------- kernel 1: norms + exact fp32 diag + normalized fp8(e4m3) copies ----------
// A: linear 256B rows, scaled by log2(e)/||a||  (GEMM result = log2e*cos -> exp2)
// B: linear 256B rows, scaled 1/||b||  (consumed direct-to-register, no swizzle)
__global__ __launch_bounds__(256) void conv_k(const float* __restrict__ o1,
                                              const float* __restrict__ o2,
                                              unsigned char* __restrict__ a8,
                                              unsigned char* __restrict__ b8,
                                              float* __restrict__ diag) {
    const int wid = threadIdx.x >> 6, lane = threadIdx.x & 63;
    const int r = blockIdx.x * 4 + wid;
    const float4* p1 = (const float4*)(o1 + (size_t)r * D);
    const float4* p2 = (const float4*)(o2 + (size_t)r * D);
    float4 v1 = p1[lane], v2 = p2[lane];
    float s1 = v1.x*v1.x + v1.y*v1.y + v1.z*v1.z + v1.w*v1.w;
    float s2 = v2.x*v2.x + v2.y*v2.y + v2.z*v2.z + v2.w*v2.w;
    float sd = v1.x*v2.x + v1.y*v2.y + v1.z*v2.z + v1.w*v2.w;
    #pragma unroll
    for (int m = 1; m < 64; m <<= 1) {
        s1 += __shfl_xor(s1, m);
        s2 += __shfl_xor(s2, m);
        sd += __shfl_xor(sd, m);
    }
    float i1 = 1.0f / sqrtf(s1);
    float i2 = 1.0f / sqrtf(s2);
    if (lane == 0) diag[r] = sd * i1 * i2;

    float a_sc = i1 * LOG2E;
    {   // A linear fp8
        int pa = __builtin_amdgcn_cvt_pk_fp8_f32(v1.x * a_sc, v1.y * a_sc, 0, false);
        pa     = __builtin_amdgcn_cvt_pk_fp8_f32(v1.z * a_sc, v1.w * a_sc, pa, true);
        *(int*)(a8 + (size_t)r * 256 + lane * 4) = pa;
    }
    {   // B linear fp8
        int pb = __builtin_amdgcn_cvt_pk_fp8_f32(v2.x * i2, v2.y * i2, 0, false);
        pb     = __builtin_amdgcn_cvt_pk_fp8_f32(v2.z * i2, v2.w * i2, pb, true);
        *(int*)(b8 + (size_t)r * 256 + lane * 4) = pb;
    }
}

// ---------- kernel 2: barrier-free LDS-free MX-fp8 GEMM + row-wise sum(exp) ----------
// block: 128 rows x 1024 cols; 4 waves = 2 row x 2 col; wave tile 64 x 32
// B loaded direct global->reg, double-buffered in named sets; compiler schedules.
__global__ __launch_bounds__(256, 2) void gemm12(const unsigned char* __restrict__ a8,
                                                 const unsigned char* __restrict__ b8,
                                                 float* __restrict__ s_part) {
    __shared__ float red[2][128];                   // epilogue only

    const int tid = threadIdx.x;
    const int lane = tid & 63, wid = tid >> 6;
    const int wr = wid >> 1, wc = wid & 1;          // 2 row-waves x 2 col-waves
    const int l15 = lane & 15, lk = lane >> 4;      // lk = k-group 0..3
    const int bid = blockIdx.x;
    const int panel = bid & 7, rb = bid >> 3;       // 8 XCD-pinned panels x 64 row-blocks

    const unsigned char* aG = a8 + (size_t)rb * (128 * 256);
    // per-thread B base: my column within the panel, my k-slot
    const unsigned char* bW = b8 + (size_t)(panel * 1024 + wc * 32 + l15) * 256 + lk * 32;

    // A fragments: rows wr*64 + mr*16 + l15; k-bytes kh*128 + lk*32
    i32x8 af[4][2];
    #pragma unroll
    for (int mr = 0; mr < 4; ++mr)
        #pragma unroll
        for (int kh = 0; kh < 2; ++kh)
            af[mr][kh] = *(const i32x8*)(aG + (size_t)(wr * 64 + mr * 16 + l15) * 256
                                            + kh * 128 + lk * 32);

    float srow[4][4];
    #pragma unroll
    for (int mr = 0; mr < 4; ++mr)
        #pragma unroll
        for (int rg = 0; rg < 4; ++rg) srow[mr][rg] = 0.f;

#define LOADB(DST, P)                                                           \
    {                                                                           \
        _Pragma("unroll")                                                       \
        for (int kh_ = 0; kh_ < 2; ++kh_)                                       \
            _Pragma("unroll")                                                   \
            for (int nc_ = 0; nc_ < 2; ++nc_)                                   \
                DST[kh_][nc_] = *(const i32x8*)(bW + (size_t)((P) * 64 + nc_ * 16) * 256 \
                                                   + kh_ * 128);                \
    }

#define COMPUTE(BB)                                                             \
    {                                                                           \
        f32x4 acc[4][2];                                                        \
        _Pragma("unroll")                                                       \
        for (int mr_ = 0; mr_ < 4; ++mr_)                                       \
            _Pragma("unroll")                                                   \
            for (int nc_ = 0; nc_ < 2; ++nc_)                                   \
                acc[mr_][nc_] = (f32x4){0.f, 0.f, 0.f, 0.f};                    \
        __builtin_amdgcn_s_setprio(1);                                          \
        _Pragma("unroll")                                                       \
        for (int kh_ = 0; kh_ < 2; ++kh_)                                       \
            _Pragma("unroll")                                                   \
            for (int nc_ = 0; nc_ < 2; ++nc_)                                   \
                _Pragma("unroll")                                               \
                for (int mr_ = 0; mr_ < 4; ++mr_)                               \
                    acc[mr_][nc_] = __builtin_amdgcn_mfma_scale_f32_16x16x128_f8f6f4( \
                        af[mr_][kh_], BB[kh_][nc_], acc[mr_][nc_],              \
                        0, 0, 0, 0x7F, 0, 0x7F);                                \
        __builtin_amdgcn_s_setprio(0);                                          \
        _Pragma("unroll")                                                       \
        for (int mr_ = 0; mr_ < 4; ++mr_)                                       \
            _Pragma("unroll")                                                   \
            for (int rg_ = 0; rg_ < 4; ++rg_)                                   \
                srow[mr_][rg_] += exp2f(acc[mr_][0][rg_]) + exp2f(acc[mr_][1][rg_]); \
    }

    i32x8 bbA[2][2], bbB[2][2];
    LOADB(bbA, 0);

    #pragma unroll 1
    for (int p = 0; p < NCHK; p += 2) {
        if (p + 1 < NCHK) LOADB(bbB, p + 1);
        COMPUTE(bbA);
        if (p + 2 < NCHK) LOADB(bbA, p + 2);
        if (p + 1 < NCHK) COMPUTE(bbB);
    }
#undef LOADB
#undef COMPUTE

    // reduce across the 16 column-lanes (C layout: col = lane&15, row = lk*4+rg)
    #pragma unroll
    for (int mr = 0; mr < 4; ++mr)
        #pragma unroll
        for (int rg = 0; rg < 4; ++rg) {
            float v = srow[mr][rg];
            v += __shfl_xor(v, 1);
            v += __shfl_xor(v, 2);
            v += __shfl_xor(v, 4);
            v += __shfl_xor(v, 8);
            srow[mr][rg] = v;
        }
    if (l15 == 0) {
        #pragma unroll
        for (int mr = 0; mr < 4; ++mr)
            #pragma unroll
            for (int rg = 0; rg < 4; ++rg)
                red[wc][wr * 64 + mr * 16 + lk * 4 + rg] = srow[mr][rg];
    }
    __syncthreads();
    if (tid < 128) {
        s_part[(size_t)panel * N + rb * 128 + tid] = red[0][tid] + red[1][tid];
    }
}

// ---------- kernel 3: per-row loss ----------
__global__ __launch_bounds__(128) void rowloss3(const float* __restrict__ s_part,
                                                const float* __restrict__ diag,
                                                float* __restrict__ partial) {
    const int t = threadIdx.x, rb = blockIdx.x;
    float s = 0.f;
    #pragma unroll
    for (int sp = 0; sp < SP; ++sp)
        s += s_part[(size_t)sp * N + rb * 128 + t];
    float loss = logf(s) - diag[rb * 128 + t];
    #pragma unroll
    for (int m = 1; m < 64; m <<= 1) loss += __shfl_xor(loss, m);
    __shared__ float redl[2];
    if ((t & 63) == 0) redl[t >> 6] = loss;
    __syncthreads();
    if (t == 0) partial[rb] = redl[0] + redl[1];
}

// ---------- kernel 4: final mean ----------
__global__ __launch_bounds__(64) void final_k(const float* __restrict__ partial,
                                              float* __restrict__ out) {
    const int t = threadIdx.x;
    float v = partial[t];
    #pragma unroll
    for (int m = 1; m < 64; m <<= 1) v += __shfl_xor(v, m);
    if (t == 0) out[0] = v / (float)N;
}

extern "C" void kernel_launch(void* const* d_in, const int* in_sizes, int n_in,
                              void* d_out, int out_size, void* d_ws, size_t ws_size,
                              hipStream_t stream) {
    const float* o1 = (const float*)d_in[0];
    const float* o2 = (const float*)d_in[1];

    unsigned char* w = (unsigned char*)d_ws;
    unsigned char* a8 = w;                                     // 2 MB
    unsigned char* b8 = w + (size_t)2 * 1024 * 1024;           // 2 MB
    float* diag    = (float*)(w + (size_t)4 * 1024 * 1024);    // 32 KB
    float* s_part  = diag + N;                                 // SP*N = 256 KB
    float* partial = s_part + (size_t)SP * N;                  // 256 B

    conv_k<<<N / 4, 256, 0, stream>>>(o1, o2, a8, b8, diag);
    gemm12<<<512, 256, 0, stream>>>(a8, b8, s_part);
    rowloss3<<<N / 128, 128, 0, stream>>>(s_part, diag, partial);
    final_k<<<1, 64, 0, stream>>>(partial, (float*)d_out);
}